// Round 2
// baseline (693.320 us; speedup 1.0000x reference)
//
#include <hip/hip_runtime.h>
#include <cstdint>

#define D_DIM 1024
#define V_DIM 32000
#define S_DIM 512
#define M_TOK 77
#define ROWS 2464
#define ROWS_PAD 2560

// ---- gemm2 (256^2, BK=32, 4-buffer ring, counted vmcnt) geometry ----
#define G2_BM 256
#define G2_BN 256
#define G2_BK 32
#define G2_MT (ROWS_PAD / G2_BM)  // 10
#define G2_NT (V_DIM / G2_BN)     // 125
#define G2_NWG (G2_MT * G2_NT)    // 1250
#define G2_KT (D_DIM / G2_BK)     // 32 K-tiles

typedef __attribute__((ext_vector_type(8))) short bf16x8;
typedef __attribute__((ext_vector_type(4))) float f32x4;
typedef __attribute__((ext_vector_type(4))) uint16_t u16x4;

__device__ __forceinline__ uint16_t f2bf(float f) {
    union { float f; uint32_t u; } w; w.f = f;
    uint32_t r = (w.u + 0x7FFFu + ((w.u >> 16) & 1u)) >> 16;
    return (uint16_t)r;
}

__device__ __forceinline__ void async_copy16(const uint16_t* g, uint16_t* l) {
    __builtin_amdgcn_global_load_lds((const __attribute__((address_space(1))) void*)g,
                                     (__attribute__((address_space(3))) void*)l,
                                     16, 0, 0);
}

// ------- transpose+cast: in fp32 [R][C] -> out bf16 [C][R], 64x64 tiles ----
__global__ __launch_bounds__(256) void transpose_f32_bf16(const float* __restrict__ in,
                                                          uint16_t* __restrict__ out,
                                                          int R, int C) {
    __shared__ uint16_t tile[64][65];
    const int c0 = blockIdx.x * 64, r0 = blockIdx.y * 64;
    const int t  = threadIdx.x;
    const int lr = t >> 4;          // 0..15
    const int lc = (t & 15) * 4;    // 0..60
#pragma unroll
    for (int p = 0; p < 4; ++p) {
        const float* src = in + (size_t)(r0 + p * 16 + lr) * C + c0 + lc;
        f32x4 v = *(const f32x4*)src;
        tile[p * 16 + lr][lc + 0] = f2bf(v.x);
        tile[p * 16 + lr][lc + 1] = f2bf(v.y);
        tile[p * 16 + lr][lc + 2] = f2bf(v.z);
        tile[p * 16 + lr][lc + 3] = f2bf(v.w);
    }
    __syncthreads();
#pragma unroll
    for (int p = 0; p < 4; ++p) {
        const int oc = p * 16 + lr;  // col index within tile -> out row c0+oc
        u16x4 v;
        v.x = tile[lc + 0][oc];
        v.y = tile[lc + 1][oc];
        v.z = tile[lc + 2][oc];
        v.w = tile[lc + 3][oc];
        *(u16x4*)(out + (size_t)(c0 + oc) * R + r0 + lc) = v;
    }
}

// ------- gather+cast masked rows: Ag[r][:] = bf16(X[b, pos[r], :]) --------
__global__ __launch_bounds__(256) void gather_rows(const float* __restrict__ X,
                                                   const int* __restrict__ pos,
                                                   uint16_t* __restrict__ Ag) {
    const int r = blockIdx.x;
    const int t = threadIdx.x;
    size_t src = 0;
    if (r < ROWS) {
        const int b = r / M_TOK;
        const int p = pos[r];      // pos is [B][M] contiguous; flat idx == r
        src = ((size_t)b * S_DIM + p) * D_DIM;
    }
    f32x4 v = *(const f32x4*)(X + src + t * 4);
    u16x4 o;
    o.x = f2bf(v.x); o.y = f2bf(v.y); o.z = f2bf(v.z); o.w = f2bf(v.w);
    *(u16x4*)(Ag + (size_t)r * D_DIM + t * 4) = o;
}

// ------- m97-style GEMM (kept for the small GEMM1): C = A * B^T + bias ----
template <int EPI>
__global__ __launch_bounds__(256, 2) void gemm_bt(const uint16_t* __restrict__ A,
                                                  const uint16_t* __restrict__ B,
                                                  const float* __restrict__ bias,
                                                  float* __restrict__ C,
                                                  int K, int N, int MValid) {
    __shared__ uint16_t As[128 * 64];
    __shared__ uint16_t Bs[128 * 64];
    const int tid  = threadIdx.x;
    const int lane = tid & 63;
    const int wave = tid >> 6;
    const int wr   = (wave >> 1) * 64;
    const int wc   = (wave & 1) * 64;
    const int tM   = blockIdx.y * 128;
    const int tN   = blockIdx.x * 128;
    const int l15  = lane & 15;
    const int l4   = lane >> 4;

    const f32x4 zero = {0.f, 0.f, 0.f, 0.f};
    f32x4 acc[4][4];
#pragma unroll
    for (int i = 0; i < 4; ++i)
#pragma unroll
        for (int j = 0; j < 4; ++j) acc[i][j] = zero;

    const uint16_t* Agp = A + (size_t)(tM + (tid >> 3)) * K + (tid & 7) * 8;
    const uint16_t* Bgp = B + (size_t)(tN + (tid >> 3)) * K + (tid & 7) * 8;
    uint16_t* Asl = &As[tid * 8];
    uint16_t* Bsl = &Bs[tid * 8];
    const size_t rstep = (size_t)32 * K;

    for (int k0 = 0; k0 < K; k0 += 64) {
#pragma unroll
        for (int i = 0; i < 4; ++i)
            async_copy16(Agp + i * rstep + k0, Asl + i * 2048);
#pragma unroll
        for (int i = 0; i < 4; ++i)
            async_copy16(Bgp + i * rstep + k0, Bsl + i * 2048);
        __syncthreads();
#pragma unroll
        for (int kk = 0; kk < 2; ++kk) {
            bf16x8 af[4], bfr[4];
#pragma unroll
            for (int i = 0; i < 4; ++i)
                af[i] = *(const bf16x8*)&As[(wr + i * 16 + l15) * 64 + kk * 32 + l4 * 8];
#pragma unroll
            for (int j = 0; j < 4; ++j)
                bfr[j] = *(const bf16x8*)&Bs[(wc + j * 16 + l15) * 64 + kk * 32 + l4 * 8];
#pragma unroll
            for (int i = 0; i < 4; ++i)
#pragma unroll
                for (int j = 0; j < 4; ++j)
                    acc[i][j] = __builtin_amdgcn_mfma_f32_16x16x32_bf16(af[i], bfr[j],
                                                                        acc[i][j], 0, 0, 0);
        }
        __syncthreads();
    }

#pragma unroll
    for (int j = 0; j < 4; ++j) {
        const int col = tN + wc + j * 16 + l15;
        const float bv = bias[col];
#pragma unroll
        for (int i = 0; i < 4; ++i) {
            const int row0 = tM + wr + i * 16 + l4 * 4;
#pragma unroll
            for (int r = 0; r < 4; ++r) {
                const int row = row0 + r;
                float v = acc[i][j][r] + bv;
                if (EPI == 0) {
                    v = v > 0.f ? v : 0.f;
                    C[(size_t)row * N + col] = v;
                } else {
                    if (row < MValid)
                        C[(size_t)row * N + col] = v;
                }
            }
        }
    }
}

// ------- GEMM2: 256x256 tile, BK=32, 4-buffer LDS ring, counted vmcnt -----
// C[2560,32000] = A[2560,1024] * B^T[32000,1024] + bias, fp32 out, row mask.
// LDS 128 KiB = 4 ring buffers x { A[256][32] | B[256][32] } bf16.
// Stage tile T+3 at tile T's phase 0 -> ~6 phases of load cover; tile seam
// waits vmcnt(8) (only the oldest tile's 4 loads) -- NEVER drains to 0 in
// the main loop (T4).  Slot swizzle l4 ^ ((row>>1)&3) keeps ds_read_b128
// conflict-free at the 64-B row stride (2 accesses/bank).
#define G2_TILE(T, STAGE, VM)                                                              \
    do {                                                                                   \
        asm volatile("s_waitcnt vmcnt(" #VM ")" ::: "memory");                             \
        __builtin_amdgcn_s_barrier();                                                      \
        const int bufc = ((T) & 3) * 16384;                                                \
        bf16x8 af[4], bfv[4];                                                              \
        _Pragma("unroll") for (int i = 0; i < 4; ++i)                                      \
            af[i] = *(const bf16x8*)&lds[bufc + (R0 + i * 16 + l15) * 32 + swr];           \
        _Pragma("unroll") for (int j = 0; j < 4; ++j)                                      \
            bfv[j] = *(const bf16x8*)&lds[bufc + 8192 + (C0 + j * 16 + l15) * 32 + swr];   \
        if (STAGE) {                                                                       \
            const int sb = (((T) + 3) & 3) * 16384;                                        \
            const int k0 = ((T) + 3) * G2_BK;                                              \
            async_copy16(Ag0 + k0, AsD + sb);                                              \
            async_copy16(Ag1 + k0, AsD + sb + 4096);                                       \
            async_copy16(Bg0 + k0, BsD + sb);                                              \
            async_copy16(Bg1 + k0, BsD + sb + 4096);                                       \
        }                                                                                  \
        __builtin_amdgcn_s_barrier();                                                      \
        asm volatile("s_waitcnt lgkmcnt(0)" ::: "memory");                                 \
        __builtin_amdgcn_s_setprio(1);                                                     \
        _Pragma("unroll") for (int i = 0; i < 4; ++i)                                      \
            _Pragma("unroll") for (int j = 0; j < 4; ++j)                                  \
                acc[i][j] = __builtin_amdgcn_mfma_f32_16x16x32_bf16(af[i], bfv[j],         \
                                                                    acc[i][j], 0, 0, 0);   \
        __builtin_amdgcn_s_setprio(0);                                                     \
        __builtin_amdgcn_s_barrier();                                                      \
        _Pragma("unroll") for (int i = 0; i < 4; ++i)                                      \
            af[i] = *(const bf16x8*)&lds[bufc + (R0 + 64 + i * 16 + l15) * 32 + swr];      \
        __builtin_amdgcn_s_barrier();                                                      \
        asm volatile("s_waitcnt lgkmcnt(0)" ::: "memory");                                 \
        __builtin_amdgcn_s_setprio(1);                                                     \
        _Pragma("unroll") for (int i = 0; i < 4; ++i)                                      \
            _Pragma("unroll") for (int j = 0; j < 4; ++j)                                  \
                acc[4 + i][j] = __builtin_amdgcn_mfma_f32_16x16x32_bf16(af[i], bfv[j],     \
                                                                        acc[4 + i][j],    \
                                                                        0, 0, 0);          \
        __builtin_amdgcn_s_setprio(0);                                                     \
    } while (0)

__global__ __launch_bounds__(512, 2) void gemm2_256(const uint16_t* __restrict__ A,
                                                    const uint16_t* __restrict__ B,
                                                    const float* __restrict__ bias,
                                                    float* __restrict__ C,
                                                    int MValid) {
    __shared__ uint16_t lds[65536];   // 128 KiB = 4 x 32 KiB ring buffers
    const int tid  = threadIdx.x;
    const int lane = tid & 63;
    const int wave = tid >> 6;        // 0..7
    const int l15  = lane & 15;
    const int l4   = lane >> 4;       // 0..3
    const int R0   = (wave >> 2) * 128;  // wave row base (2 waves in M)
    const int C0   = (wave & 3) * 64;    // wave col base (4 waves in N)

    // T1: bijective XCD-chunked swizzle (m204); tm-fast => consecutive logical
    // blocks share the 512KB B-panel within one XCD's L2.
    const int bid = blockIdx.x;
    const int q = G2_NWG >> 3, r = G2_NWG & 7;
    const int xcd = bid & 7, lin = bid >> 3;
    const int wg = (xcd < r ? xcd * (q + 1) : r * (q + 1) + (xcd - r) * q) + lin;
    const int tM = (wg % G2_MT) * G2_BM;
    const int tN = (wg / G2_MT) * G2_BN;

    // Staging: linear LDS dest (global_load_lds requirement) + inverse-swizzled
    // GLOBAL source column.  LDS (row, physslot s) holds logical slot
    // s ^ ((row>>1)&3); rows are 32 bf16 (64 B).
    const int srow  = tid >> 2;                                   // 0..127
    const int sslot = tid & 3;                                    // 16B slot
    const int swcol = ((sslot ^ ((srow >> 1) & 3)) << 3);         // element col
    const uint16_t* Ag0 = A + (size_t)(tM + srow) * D_DIM + swcol;
    const uint16_t* Ag1 = Ag0 + (size_t)128 * D_DIM;
    const uint16_t* Bg0 = B + (size_t)(tN + srow) * D_DIM + swcol;
    const uint16_t* Bg1 = Bg0 + (size_t)128 * D_DIM;
    uint16_t* AsD = &lds[tid * 8];
    uint16_t* BsD = &lds[8192 + tid * 8];

    // swizzled read column (elements): (r>>1)&3 == (l15>>1)&3 for all rows read
    const int swr = ((l4 ^ ((l15 >> 1) & 3)) << 3);

    const f32x4 zero = {0.f, 0.f, 0.f, 0.f};
    f32x4 acc[8][4];
#pragma unroll
    for (int i = 0; i < 8; ++i)
#pragma unroll
        for (int j = 0; j < 4; ++j) acc[i][j] = zero;

    // ---- prologue: stage tiles 0,1,2 into ring buffers 0,1,2 (12 loads) ----
#pragma unroll
    for (int t = 0; t < 3; ++t) {
        const int sb = t * 16384;
        const int k0 = t * G2_BK;
        async_copy16(Ag0 + k0, AsD + sb);
        async_copy16(Ag1 + k0, AsD + sb + 4096);
        async_copy16(Bg0 + k0, BsD + sb);
        async_copy16(Bg1 + k0, BsD + sb + 4096);
    }

    // ---- main loop: tiles 0..28 stage tile T+3 and wait vmcnt(8) ----
#pragma unroll 2
    for (int T = 0; T < G2_KT - 3; ++T) {
        G2_TILE(T, true, 8);
    }
    // ---- tail: no more stages; outstanding loads decay 12 -> 8 -> 4 -> 0 ----
    G2_TILE(G2_KT - 3, false, 8);
    G2_TILE(G2_KT - 2, false, 4);
    G2_TILE(G2_KT - 1, false, 0);

    // ---- epilogue: D mapping (16x16x32): row = l4*4 + rr, col = l15 ----
#pragma unroll
    for (int j = 0; j < 4; ++j) {
        const int col = tN + C0 + j * 16 + l15;
        const float bv = bias[col];
#pragma unroll
        for (int i = 0; i < 8; ++i) {
            const int row0 = tM + R0 + i * 16 + l4 * 4;   // i=0..3 rows 0..63, i=4..7 rows 64..127
#pragma unroll
            for (int rr = 0; rr < 4; ++rr) {
                const int row = row0 + rr;
                if (row < MValid)
                    C[(size_t)row * V_DIM + col] = acc[i][j][rr] + bv;
            }
        }
    }
}

// ------- row LayerNorm: H fp32 [ROWS_PAD][1024] -> Hn bf16 ----------------
__global__ __launch_bounds__(256) void layernorm_rows(const float* __restrict__ H,
                                                      const float* __restrict__ gamma,
                                                      const float* __restrict__ beta,
                                                      uint16_t* __restrict__ Hn) {
    const int row = blockIdx.x;
    const int t   = threadIdx.x;
    const float* h = H + (size_t)row * D_DIM;
    f32x4 v = *(const f32x4*)(h + t * 4);
    float s  = v.x + v.y + v.z + v.w;
    float sq = v.x * v.x + v.y * v.y + v.z * v.z + v.w * v.w;
#pragma unroll
    for (int o = 32; o > 0; o >>= 1) {
        s  += __shfl_down(s, o, 64);
        sq += __shfl_down(sq, o, 64);
    }
    __shared__ float ss[4], sqs[4];
    if ((t & 63) == 0) { ss[t >> 6] = s; sqs[t >> 6] = sq; }
    __syncthreads();
    const float S    = ss[0] + ss[1] + ss[2] + ss[3];
    const float SQ   = sqs[0] + sqs[1] + sqs[2] + sqs[3];
    const float mean = S * (1.f / D_DIM);
    const float var  = SQ * (1.f / D_DIM) - mean * mean;
    const float rstd = rsqrtf(var + 1e-5f);
    const int c = t * 4;
    f32x4 g = *(const f32x4*)(gamma + c);
    f32x4 bt = *(const f32x4*)(beta + c);
    u16x4 o;
    o.x = f2bf((v.x - mean) * rstd * g.x + bt.x);
    o.y = f2bf((v.y - mean) * rstd * g.y + bt.y);
    o.z = f2bf((v.z - mean) * rstd * g.z + bt.z);
    o.w = f2bf((v.w - mean) * rstd * g.w + bt.w);
    *(u16x4*)(Hn + (size_t)row * D_DIM + c) = o;
}

extern "C" void kernel_launch(void* const* d_in, const int* in_sizes, int n_in,
                              void* d_out, int out_size, void* d_ws, size_t ws_size,
                              hipStream_t stream) {
    const float* X     = (const float*)d_in[0];
    const int*   mp    = (const int*)d_in[1];
    const float* W1    = (const float*)d_in[2];
    const float* b1    = (const float*)d_in[3];
    const float* gamma = (const float*)d_in[4];
    const float* beta  = (const float*)d_in[5];
    const float* W2    = (const float*)d_in[6];
    const float* b2    = (const float*)d_in[7];

    char* ws = (char*)d_ws;
    uint16_t* W2T = (uint16_t*)(ws);                                           // 65,536,000 B
    uint16_t* W1T = (uint16_t*)(ws + 65536000);                                //  2,097,152 B
    uint16_t* Ag  = (uint16_t*)(ws + 65536000 + 2097152);                      //  5,242,880 B
    uint16_t* Hn  = (uint16_t*)(ws + 65536000 + 2097152 + 5242880);            //  5,242,880 B
    float*    H   = (float*)   (ws + 65536000 + 2097152 + 5242880 + 5242880);  // 10,485,760 B

    // W2 fp32 [1024][32000] -> W2T bf16 [32000][1024]; W1 likewise
    transpose_f32_bf16<<<dim3(V_DIM / 64, D_DIM / 64), 256, 0, stream>>>(W2, W2T, D_DIM, V_DIM);
    transpose_f32_bf16<<<dim3(D_DIM / 64, D_DIM / 64), 256, 0, stream>>>(W1, W1T, D_DIM, D_DIM);
    // gather masked rows (padded to 2560 with row 0 data), cast to bf16
    gather_rows<<<ROWS_PAD, 256, 0, stream>>>(X, mp, Ag);
    // H = relu(Ag @ W1 + b1)   [2560][1024] fp32
    gemm_bt<0><<<dim3(D_DIM / 128, ROWS_PAD / 128), 256, 0, stream>>>(Ag, W1T, b1, H,
                                                                      D_DIM, D_DIM, ROWS_PAD);
    // Hn = LN(H) * gamma + beta  -> bf16
    layernorm_rows<<<ROWS_PAD, 256, 0, stream>>>(H, gamma, beta, Hn);
    // out = Hn @ W2 + b2  [2464][32000] fp32  (BK=32 ring-4 counted-vmcnt kernel)
    gemm2_256<<<dim3(G2_NWG), 512, 0, stream>>>(Hn, W2T, b2, (float*)d_out, ROWS);
}

// Round 3
// 677.906 us; speedup vs baseline: 1.0227x; 1.0227x over previous
//
#include <hip/hip_runtime.h>
#include <cstdint>

#define D_DIM 1024
#define V_DIM 32000
#define S_DIM 512
#define M_TOK 77
#define ROWS 2464
#define ROWS_PAD 2560

// ---- gemm2 (256^2, BK=32, 4-buffer ring, 1-barrier pipelined) geometry ----
#define G2_BM 256
#define G2_BN 256
#define G2_BK 32
#define G2_MT (ROWS_PAD / G2_BM)  // 10
#define G2_NT (V_DIM / G2_BN)     // 125
#define G2_NWG (G2_MT * G2_NT)    // 1250
#define G2_KT (D_DIM / G2_BK)     // 32 K-tiles

typedef __attribute__((ext_vector_type(8))) short bf16x8;
typedef __attribute__((ext_vector_type(4))) float f32x4;
typedef __attribute__((ext_vector_type(4))) uint16_t u16x4;

__device__ __forceinline__ uint16_t f2bf(float f) {
    union { float f; uint32_t u; } w; w.f = f;
    uint32_t r = (w.u + 0x7FFFu + ((w.u >> 16) & 1u)) >> 16;
    return (uint16_t)r;
}

__device__ __forceinline__ void async_copy16(const uint16_t* g, uint16_t* l) {
    __builtin_amdgcn_global_load_lds((const __attribute__((address_space(1))) void*)g,
                                     (__attribute__((address_space(3))) void*)l,
                                     16, 0, 0);
}

// ------- transpose+cast: in fp32 [R][C] -> out bf16 [C][R], 64x64 tiles ----
__global__ __launch_bounds__(256) void transpose_f32_bf16(const float* __restrict__ in,
                                                          uint16_t* __restrict__ out,
                                                          int R, int C) {
    __shared__ uint16_t tile[64][65];
    const int c0 = blockIdx.x * 64, r0 = blockIdx.y * 64;
    const int t  = threadIdx.x;
    const int lr = t >> 4;          // 0..15
    const int lc = (t & 15) * 4;    // 0..60
#pragma unroll
    for (int p = 0; p < 4; ++p) {
        const float* src = in + (size_t)(r0 + p * 16 + lr) * C + c0 + lc;
        f32x4 v = *(const f32x4*)src;
        tile[p * 16 + lr][lc + 0] = f2bf(v.x);
        tile[p * 16 + lr][lc + 1] = f2bf(v.y);
        tile[p * 16 + lr][lc + 2] = f2bf(v.z);
        tile[p * 16 + lr][lc + 3] = f2bf(v.w);
    }
    __syncthreads();
#pragma unroll
    for (int p = 0; p < 4; ++p) {
        const int oc = p * 16 + lr;  // col index within tile -> out row c0+oc
        u16x4 v;
        v.x = tile[lc + 0][oc];
        v.y = tile[lc + 1][oc];
        v.z = tile[lc + 2][oc];
        v.w = tile[lc + 3][oc];
        *(u16x4*)(out + (size_t)(c0 + oc) * R + r0 + lc) = v;
    }
}

// ------- gather+cast masked rows: Ag[r][:] = bf16(X[b, pos[r], :]) --------
__global__ __launch_bounds__(256) void gather_rows(const float* __restrict__ X,
                                                   const int* __restrict__ pos,
                                                   uint16_t* __restrict__ Ag) {
    const int r = blockIdx.x;
    const int t = threadIdx.x;
    size_t src = 0;
    if (r < ROWS) {
        const int b = r / M_TOK;
        const int p = pos[r];      // pos is [B][M] contiguous; flat idx == r
        src = ((size_t)b * S_DIM + p) * D_DIM;
    }
    f32x4 v = *(const f32x4*)(X + src + t * 4);
    u16x4 o;
    o.x = f2bf(v.x); o.y = f2bf(v.y); o.z = f2bf(v.z); o.w = f2bf(v.w);
    *(u16x4*)(Ag + (size_t)r * D_DIM + t * 4) = o;
}

// ------- m97-style GEMM (kept for the small GEMM1): C = A * B^T + bias ----
template <int EPI>
__global__ __launch_bounds__(256, 2) void gemm_bt(const uint16_t* __restrict__ A,
                                                  const uint16_t* __restrict__ B,
                                                  const float* __restrict__ bias,
                                                  float* __restrict__ C,
                                                  int K, int N, int MValid) {
    __shared__ uint16_t As[128 * 64];
    __shared__ uint16_t Bs[128 * 64];
    const int tid  = threadIdx.x;
    const int lane = tid & 63;
    const int wave = tid >> 6;
    const int wr   = (wave >> 1) * 64;
    const int wc   = (wave & 1) * 64;
    const int tM   = blockIdx.y * 128;
    const int tN   = blockIdx.x * 128;
    const int l15  = lane & 15;
    const int l4   = lane >> 4;

    const f32x4 zero = {0.f, 0.f, 0.f, 0.f};
    f32x4 acc[4][4];
#pragma unroll
    for (int i = 0; i < 4; ++i)
#pragma unroll
        for (int j = 0; j < 4; ++j) acc[i][j] = zero;

    const uint16_t* Agp = A + (size_t)(tM + (tid >> 3)) * K + (tid & 7) * 8;
    const uint16_t* Bgp = B + (size_t)(tN + (tid >> 3)) * K + (tid & 7) * 8;
    uint16_t* Asl = &As[tid * 8];
    uint16_t* Bsl = &Bs[tid * 8];
    const size_t rstep = (size_t)32 * K;

    for (int k0 = 0; k0 < K; k0 += 64) {
#pragma unroll
        for (int i = 0; i < 4; ++i)
            async_copy16(Agp + i * rstep + k0, Asl + i * 2048);
#pragma unroll
        for (int i = 0; i < 4; ++i)
            async_copy16(Bgp + i * rstep + k0, Bsl + i * 2048);
        __syncthreads();
#pragma unroll
        for (int kk = 0; kk < 2; ++kk) {
            bf16x8 af[4], bfr[4];
#pragma unroll
            for (int i = 0; i < 4; ++i)
                af[i] = *(const bf16x8*)&As[(wr + i * 16 + l15) * 64 + kk * 32 + l4 * 8];
#pragma unroll
            for (int j = 0; j < 4; ++j)
                bfr[j] = *(const bf16x8*)&Bs[(wc + j * 16 + l15) * 64 + kk * 32 + l4 * 8];
#pragma unroll
            for (int i = 0; i < 4; ++i)
#pragma unroll
                for (int j = 0; j < 4; ++j)
                    acc[i][j] = __builtin_amdgcn_mfma_f32_16x16x32_bf16(af[i], bfr[j],
                                                                        acc[i][j], 0, 0, 0);
        }
        __syncthreads();
    }

#pragma unroll
    for (int j = 0; j < 4; ++j) {
        const int col = tN + wc + j * 16 + l15;
        const float bv = bias[col];
#pragma unroll
        for (int i = 0; i < 4; ++i) {
            const int row0 = tM + wr + i * 16 + l4 * 4;
#pragma unroll
            for (int r = 0; r < 4; ++r) {
                const int row = row0 + r;
                float v = acc[i][j][r] + bv;
                if (EPI == 0) {
                    v = v > 0.f ? v : 0.f;
                    C[(size_t)row * N + col] = v;
                } else {
                    if (row < MValid)
                        C[(size_t)row * N + col] = v;
                }
            }
        }
    }
}

// ------- GEMM2: 256x256 tile, BK=32, 4-buffer LDS ring, 1 barrier/tile ----
// Register-level pipeline: tile T's fragments are loaded during tile T-1, so
// MFMA(T) starts with near-zero lgkm wait and reads(T+1)'s LDS service hides
// under the CU's MFMA drain.  One s_barrier + one counted vmcnt per tile;
// vmcnt never drains to 0 in the main loop (T4).
#define G2_SEAM(VM)                                                  \
    asm volatile("s_waitcnt vmcnt(" #VM ")" ::: "memory");           \
    __builtin_amdgcn_s_barrier();

#define G2_STAGE(T)                                                  \
    do {                                                             \
        const int sb_ = ((T) & 3) * 16384;                           \
        const int k0_ = (T) * G2_BK;                                 \
        async_copy16(Ag0 + k0_, AsD + sb_);                          \
        async_copy16(Ag1 + k0_, AsD + sb_ + 4096);                   \
        async_copy16(Bg0 + k0_, BsD + sb_);                          \
        async_copy16(Bg1 + k0_, BsD + sb_ + 4096);                   \
    } while (0)

#define G2_MFMA()                                                                          \
    do {                                                                                   \
        __builtin_amdgcn_s_setprio(1);                                                     \
        _Pragma("unroll") for (int i = 0; i < 4; ++i)                                      \
            _Pragma("unroll") for (int j = 0; j < 4; ++j)                                  \
                acc[i][j] = __builtin_amdgcn_mfma_f32_16x16x32_bf16(fa0[i], fb[j],         \
                                                                    acc[i][j], 0, 0, 0);   \
        _Pragma("unroll") for (int i = 0; i < 4; ++i)                                      \
            _Pragma("unroll") for (int j = 0; j < 4; ++j)                                  \
                acc[4 + i][j] = __builtin_amdgcn_mfma_f32_16x16x32_bf16(fa1[i], fb[j],     \
                                                                        acc[4 + i][j],     \
                                                                        0, 0, 0);          \
        __builtin_amdgcn_s_setprio(0);                                                     \
    } while (0)

#define G2_READS(T)                                                                        \
    do {                                                                                   \
        const int bufc_ = ((T) & 3) * 16384;                                               \
        _Pragma("unroll") for (int i = 0; i < 4; ++i)                                      \
            fa0[i] = *(const bf16x8*)&lds[bufc_ + (R0 + i * 16 + l15) * 32 + swr];         \
        _Pragma("unroll") for (int i = 0; i < 4; ++i)                                      \
            fa1[i] = *(const bf16x8*)&lds[bufc_ + (R0 + 64 + i * 16 + l15) * 32 + swr];    \
        _Pragma("unroll") for (int j = 0; j < 4; ++j)                                      \
            fb[j] = *(const bf16x8*)&lds[bufc_ + 8192 + (C0 + j * 16 + l15) * 32 + swr];   \
    } while (0)

__global__ __launch_bounds__(512, 2) void gemm2_256(const uint16_t* __restrict__ A,
                                                    const uint16_t* __restrict__ B,
                                                    const float* __restrict__ bias,
                                                    float* __restrict__ C,
                                                    int MValid) {
    __shared__ uint16_t lds[65536];   // 128 KiB = 4 x 32 KiB ring buffers
    const int tid  = threadIdx.x;
    const int lane = tid & 63;
    const int wave = tid >> 6;        // 0..7
    const int l15  = lane & 15;
    const int l4   = lane >> 4;       // 0..3
    const int R0   = (wave >> 2) * 128;  // wave row base (2 waves in M)
    const int C0   = (wave & 3) * 64;    // wave col base (4 waves in N)

    // T1: bijective XCD-chunked swizzle (m204); tM-fast => consecutive logical
    // blocks share the 512KB B-panel within one XCD's L2.
    const int bid = blockIdx.x;
    const int q = G2_NWG >> 3, r = G2_NWG & 7;
    const int xcd = bid & 7, lin = bid >> 3;
    const int wg = (xcd < r ? xcd * (q + 1) : r * (q + 1) + (xcd - r) * q) + lin;
    const int tM = (wg % G2_MT) * G2_BM;
    const int tN = (wg / G2_MT) * G2_BN;

    // Staging: linear LDS dest (global_load_lds requirement) + inverse-swizzled
    // GLOBAL source column.  LDS (row, physslot s) holds logical slot
    // s ^ ((row>>1)&3); rows are 32 bf16 (64 B).
    const int srow  = tid >> 2;                                   // 0..127
    const int sslot = tid & 3;                                    // 16B slot
    const int swcol = ((sslot ^ ((srow >> 1) & 3)) << 3);         // element col
    const uint16_t* Ag0 = A + (size_t)(tM + srow) * D_DIM + swcol;
    const uint16_t* Ag1 = Ag0 + (size_t)128 * D_DIM;
    const uint16_t* Bg0 = B + (size_t)(tN + srow) * D_DIM + swcol;
    const uint16_t* Bg1 = Bg0 + (size_t)128 * D_DIM;
    uint16_t* AsD = &lds[tid * 8];
    uint16_t* BsD = &lds[8192 + tid * 8];

    // swizzled read column (elements): (r>>1)&3 == (l15>>1)&3 for all rows read
    const int swr = ((l4 ^ ((l15 >> 1) & 3)) << 3);

    const f32x4 zero = {0.f, 0.f, 0.f, 0.f};
    f32x4 acc[8][4];
#pragma unroll
    for (int i = 0; i < 8; ++i)
#pragma unroll
        for (int j = 0; j < 4; ++j) acc[i][j] = zero;

    bf16x8 fa0[4], fa1[4], fb[4];

    // ---- prologue: stage tiles 0,1,2 into ring buffers 0,1,2 (12 loads) ----
#pragma unroll
    for (int t = 0; t < 3; ++t) {
        const int sb = t * 16384;
        const int k0 = t * G2_BK;
        async_copy16(Ag0 + k0, AsD + sb);
        async_copy16(Ag1 + k0, AsD + sb + 4096);
        async_copy16(Bg0 + k0, BsD + sb);
        async_copy16(Bg1 + k0, BsD + sb + 4096);
    }
    G2_SEAM(8);        // tile 0 landed (tiles 1,2 still in flight)
    G2_READS(0);       // preload tile 0 fragments into registers

    // ---- main loop: one barrier + one vmcnt(4) per tile, never drains ----
#pragma unroll 4
    for (int T = 0; T < G2_KT - 3; ++T) {   // T = 0..28
        G2_SEAM(4);        // tile T+1 landed (tile T+2 in flight)
        G2_STAGE(T + 3);   // issue next stage early (outstanding <= 8)
        G2_MFMA();         // consume regs(T); compiler inserts counted lgkm
        G2_READS(T + 1);   // LDS service hides under CU MFMA drain
    }
    // ---- tail: T = 29, 30, 31 ----
    G2_SEAM(4);            // tile 30 landed (tile 31 in flight)
    G2_MFMA();             // MFMA(29)
    G2_READS(30);
    G2_SEAM(0);            // tile 31 landed
    G2_MFMA();             // MFMA(30)
    G2_READS(31);
    G2_MFMA();             // MFMA(31)

    // ---- epilogue: D mapping (16x16x32): row = l4*4 + rr, col = l15 ----
#pragma unroll
    for (int j = 0; j < 4; ++j) {
        const int col = tN + C0 + j * 16 + l15;
        const float bv = bias[col];
#pragma unroll
        for (int i = 0; i < 8; ++i) {
            const int row0 = tM + R0 + i * 16 + l4 * 4;   // i=0..3 rows 0..63, i=4..7 rows 64..127
#pragma unroll
            for (int rr = 0; rr < 4; ++rr) {
                const int row = row0 + rr;
                if (row < MValid)
                    C[(size_t)row * V_DIM + col] = acc[i][j][rr] + bv;
            }
        }
    }
}

// ------- row LayerNorm: H fp32 [ROWS_PAD][1024] -> Hn bf16 ----------------
__global__ __launch_bounds__(256) void layernorm_rows(const float* __restrict__ H,
                                                      const float* __restrict__ gamma,
                                                      const float* __restrict__ beta,
                                                      uint16_t* __restrict__ Hn) {
    const int row = blockIdx.x;
    const int t   = threadIdx.x;
    const float* h = H + (size_t)row * D_DIM;
    f32x4 v = *(const f32x4*)(h + t * 4);
    float s  = v.x + v.y + v.z + v.w;
    float sq = v.x * v.x + v.y * v.y + v.z * v.z + v.w * v.w;
#pragma unroll
    for (int o = 32; o > 0; o >>= 1) {
        s  += __shfl_down(s, o, 64);
        sq += __shfl_down(sq, o, 64);
    }
    __shared__ float ss[4], sqs[4];
    if ((t & 63) == 0) { ss[t >> 6] = s; sqs[t >> 6] = sq; }
    __syncthreads();
    const float S    = ss[0] + ss[1] + ss[2] + ss[3];
    const float SQ   = sqs[0] + sqs[1] + sqs[2] + sqs[3];
    const float mean = S * (1.f / D_DIM);
    const float var  = SQ * (1.f / D_DIM) - mean * mean;
    const float rstd = rsqrtf(var + 1e-5f);
    const int c = t * 4;
    f32x4 g = *(const f32x4*)(gamma + c);
    f32x4 bt = *(const f32x4*)(beta + c);
    u16x4 o;
    o.x = f2bf((v.x - mean) * rstd * g.x + bt.x);
    o.y = f2bf((v.y - mean) * rstd * g.y + bt.y);
    o.z = f2bf((v.z - mean) * rstd * g.z + bt.z);
    o.w = f2bf((v.w - mean) * rstd * g.w + bt.w);
    *(u16x4*)(Hn + (size_t)row * D_DIM + c) = o;
}

extern "C" void kernel_launch(void* const* d_in, const int* in_sizes, int n_in,
                              void* d_out, int out_size, void* d_ws, size_t ws_size,
                              hipStream_t stream) {
    const float* X     = (const float*)d_in[0];
    const int*   mp    = (const int*)d_in[1];
    const float* W1    = (const float*)d_in[2];
    const float* b1    = (const float*)d_in[3];
    const float* gamma = (const float*)d_in[4];
    const float* beta  = (const float*)d_in[5];
    const float* W2    = (const float*)d_in[6];
    const float* b2    = (const float*)d_in[7];

    char* ws = (char*)d_ws;
    uint16_t* W2T = (uint16_t*)(ws);                                           // 65,536,000 B
    uint16_t* W1T = (uint16_t*)(ws + 65536000);                                //  2,097,152 B
    uint16_t* Ag  = (uint16_t*)(ws + 65536000 + 2097152);                      //  5,242,880 B
    uint16_t* Hn  = (uint16_t*)(ws + 65536000 + 2097152 + 5242880);            //  5,242,880 B
    float*    H   = (float*)   (ws + 65536000 + 2097152 + 5242880 + 5242880);  // 10,485,760 B

    // W2 fp32 [1024][32000] -> W2T bf16 [32000][1024]; W1 likewise
    transpose_f32_bf16<<<dim3(V_DIM / 64, D_DIM / 64), 256, 0, stream>>>(W2, W2T, D_DIM, V_DIM);
    transpose_f32_bf16<<<dim3(D_DIM / 64, D_DIM / 64), 256, 0, stream>>>(W1, W1T, D_DIM, D_DIM);
    // gather masked rows (padded to 2560 with row 0 data), cast to bf16
    gather_rows<<<ROWS_PAD, 256, 0, stream>>>(X, mp, Ag);
    // H = relu(Ag @ W1 + b1)   [2560][1024] fp32
    gemm_bt<0><<<dim3(D_DIM / 128, ROWS_PAD / 128), 256, 0, stream>>>(Ag, W1T, b1, H,
                                                                      D_DIM, D_DIM, ROWS_PAD);
    // Hn = LN(H) * gamma + beta  -> bf16
    layernorm_rows<<<ROWS_PAD, 256, 0, stream>>>(H, gamma, beta, Hn);
    // out = Hn @ W2 + b2  [2464][32000] fp32  (1-barrier pipelined kernel)
    gemm2_256<<<dim3(G2_NWG), 512, 0, stream>>>(Hn, W2T, b2, (float*)d_out, ROWS);
}